// Round 1
// baseline (48.602 us; speedup 1.0000x reference)
//
#include <hip/hip_runtime.h>
#include <hip/hip_bf16.h>

typedef __attribute__((ext_vector_type(8))) short short8;
typedef __attribute__((ext_vector_type(4))) float f32x4;

// fp32 -> bf16 round-to-nearest-even (finite inputs)
__device__ __forceinline__ unsigned short f2bf(float f) {
    union { float f; unsigned int u; } v; v.f = f;
    unsigned int u = v.u;
    u = (u + 0x7FFFu + ((u >> 16) & 1u)) >> 16;
    return (unsigned short)u;
}

// ---------------------------------------------------------------------------
// Kernel 1: x[b][c][h][w] f32  ->  xt[h][w][c][b] bf16
// grid (32 h, 8 cgroup), 256 threads. LDS tile [32 w][8 c][64 b], stride 520.
// ---------------------------------------------------------------------------
__global__ __launch_bounds__(256) void k_xt(const float* __restrict__ x,
                                            unsigned short* __restrict__ xt) {
    const int h  = blockIdx.x;   // 0..31
    const int cg = blockIdx.y;   // 0..7
    const int t  = threadIdx.x;
    __shared__ unsigned short L[32 * 520];  // [w][c*64+b], padded row stride

    // load phase: coalesced along w
    #pragma unroll
    for (int i = 0; i < 16; ++i) {
        int s   = t + i * 256;        // 0..4095
        int row = s >> 3;             // 0..511 -> (b,c)
        int wq  = s & 7;              // 0..7 (quad of w)
        int b = row >> 3, c = row & 7;
        const f32x4 v = *(const f32x4*)(x + (((size_t)(b * 64 + cg * 8 + c) * 32 + h) * 32 + wq * 4));
        int base = c * 64 + b;
        L[(wq * 4 + 0) * 520 + base] = f2bf(v[0]);
        L[(wq * 4 + 1) * 520 + base] = f2bf(v[1]);
        L[(wq * 4 + 2) * 520 + base] = f2bf(v[2]);
        L[(wq * 4 + 3) * 520 + base] = f2bf(v[3]);
    }
    __syncthreads();
    // store phase: contiguous 1KB per w
    #pragma unroll
    for (int i = 0; i < 8; ++i) {
        int s  = t + i * 256;   // 0..2047
        int w  = s >> 6;        // 0..31
        int ch = s & 63;        // 0..63 (8-element chunk)
        short8 v = *(const short8*)&L[w * 520 + ch * 8];
        *(short8*)(xt + (((size_t)(h * 32 + w) * 64 + cg * 8) * 64 + ch * 8)) = v;
    }
}

// ---------------------------------------------------------------------------
// Kernel 2: per-location GEMM. 1024 blocks (one per (oh,ow)), 256 threads.
// out_tile[b][o] = sum_k cols[b][k] * w[l][o][k], k natural (c*9+kh*3+kw).
// A from xt (gather, b16 scatter into LDS), B coalesced from weights.
// Writes ws2[l][b][o] f32 (+bias), coalesced.
// ---------------------------------------------------------------------------
__global__ __launch_bounds__(256) void k_main(const float* __restrict__ wgt,
                                              const unsigned short* __restrict__ xt,
                                              const float* __restrict__ bias,
                                              float* __restrict__ ws2) {
    const int l  = blockIdx.x;          // 0..1023
    const int oh = l >> 5, ow = l & 31;
    const int t  = threadIdx.x;
    const int wave = t >> 6, lane = t & 63;
    const int wm = wave >> 1, wn = wave & 1;

    __shared__ unsigned short Ash[64 * 72];  // [b][k], +8 pad
    __shared__ unsigned short Bsh[64 * 72];  // [o][k], +8 pad

    f32x4 acc[2][2];
    #pragma unroll
    for (int i = 0; i < 2; ++i)
        #pragma unroll
        for (int j = 0; j < 2; ++j)
            acc[i][j] = (f32x4){0.f, 0.f, 0.f, 0.f};

    const float* wslab = wgt + (size_t)l * (64 * 576);
    const int b0 = wave * 16;           // this wave stages b-quarter
    const int o  = t >> 2, kp = t & 3;  // B staging assignment

    for (int kt = 0; kt < 9; ++kt) {
        // ---- stage A: lane -> column kk, wave -> 16 b rows ----
        {
            int kk = kt * 64 + lane;          // 0..575
            int c  = kk / 9;
            int r  = kk - c * 9;
            int kh = r / 3;
            int kw = r - kh * 3;
            int hh = oh + kh - 1;
            int ww = ow + kw - 1;
            short8 va = {0,0,0,0,0,0,0,0};
            short8 vb = {0,0,0,0,0,0,0,0};
            if ((unsigned)hh < 32u && (unsigned)ww < 32u) {
                const unsigned short* src = xt + (((size_t)(hh * 32 + ww) * 64 + c) * 64 + b0);
                va = *(const short8*)src;
                vb = *(const short8*)(src + 8);
            }
            #pragma unroll
            for (int j = 0; j < 8; ++j) Ash[(b0 + j) * 72 + lane] = (unsigned short)va[j];
            #pragma unroll
            for (int j = 0; j < 8; ++j) Ash[(b0 + 8 + j) * 72 + lane] = (unsigned short)vb[j];
        }
        // ---- stage B: coalesced 16 floats per thread ----
        {
            const f32x4* bp = (const f32x4*)(wslab + o * 576 + kt * 64 + kp * 16);
            f32x4 f0 = bp[0], f1 = bp[1], f2 = bp[2], f3 = bp[3];
            short8 p0, p1;
            p0[0] = (short)f2bf(f0[0]); p0[1] = (short)f2bf(f0[1]);
            p0[2] = (short)f2bf(f0[2]); p0[3] = (short)f2bf(f0[3]);
            p0[4] = (short)f2bf(f1[0]); p0[5] = (short)f2bf(f1[1]);
            p0[6] = (short)f2bf(f1[2]); p0[7] = (short)f2bf(f1[3]);
            p1[0] = (short)f2bf(f2[0]); p1[1] = (short)f2bf(f2[1]);
            p1[2] = (short)f2bf(f2[2]); p1[3] = (short)f2bf(f2[3]);
            p1[4] = (short)f2bf(f3[0]); p1[5] = (short)f2bf(f3[1]);
            p1[6] = (short)f2bf(f3[2]); p1[7] = (short)f2bf(f3[3]);
            unsigned short* bdst = &Bsh[o * 72 + kp * 16];
            *(short8*)bdst       = p0;
            *(short8*)(bdst + 8) = p1;
        }
        __syncthreads();
        // ---- MFMA: 2 k-steps of 32 ----
        #pragma unroll
        for (int ks = 0; ks < 2; ++ks) {
            int kof = ks * 32 + (lane >> 4) * 8;
            short8 a0 = *(const short8*)&Ash[(wm * 32 + (lane & 15)) * 72 + kof];
            short8 a1 = *(const short8*)&Ash[(wm * 32 + 16 + (lane & 15)) * 72 + kof];
            short8 q0 = *(const short8*)&Bsh[(wn * 32 + (lane & 15)) * 72 + kof];
            short8 q1 = *(const short8*)&Bsh[(wn * 32 + 16 + (lane & 15)) * 72 + kof];
            acc[0][0] = __builtin_amdgcn_mfma_f32_16x16x32_bf16(a0, q0, acc[0][0], 0, 0, 0);
            acc[0][1] = __builtin_amdgcn_mfma_f32_16x16x32_bf16(a0, q1, acc[0][1], 0, 0, 0);
            acc[1][0] = __builtin_amdgcn_mfma_f32_16x16x32_bf16(a1, q0, acc[1][0], 0, 0, 0);
            acc[1][1] = __builtin_amdgcn_mfma_f32_16x16x32_bf16(a1, q1, acc[1][1], 0, 0, 0);
        }
        __syncthreads();
    }

    // ---- epilogue: +bias, write ws2[l][b][o] ----
    const int col = lane & 15;
    const int rq  = (lane >> 4) * 4;
    #pragma unroll
    for (int j = 0; j < 2; ++j) {
        int n = wn * 32 + j * 16 + col;
        float bv = bias[n * 1024 + l];
        #pragma unroll
        for (int i = 0; i < 2; ++i) {
            int mbase = wm * 32 + i * 16 + rq;
            #pragma unroll
            for (int q = 0; q < 4; ++q) {
                ws2[(size_t)l * 4096 + (size_t)(mbase + q) * 64 + n] = acc[i][j][q] + bv;
            }
        }
    }
}

// ---------------------------------------------------------------------------
// Kernel 3: ws2[1024 l][4096 m] -> out[4096 m][1024 l]  (tiled transpose)
// ---------------------------------------------------------------------------
__global__ __launch_bounds__(256) void k_out(const float* __restrict__ ws2,
                                             float* __restrict__ out) {
    const int bx = blockIdx.x;
    const int lt = bx & 15;    // l tile (16)
    const int mt = bx >> 4;    // m tile (64)
    const int t  = threadIdx.x;
    __shared__ float T[64 * 65];
    const int l0 = lt * 64, m0 = mt * 64;

    #pragma unroll
    for (int i = 0; i < 16; ++i) {
        int lr = (t >> 6) + i * 4;   // 0..63
        int m  = t & 63;
        T[lr * 65 + m] = ws2[(size_t)(l0 + lr) * 4096 + m0 + m];
    }
    __syncthreads();
    #pragma unroll
    for (int i = 0; i < 16; ++i) {
        int mr = (t >> 6) + i * 4;
        int lc = t & 63;
        out[(size_t)(m0 + mr) * 1024 + l0 + lc] = T[lc * 65 + mr];
    }
}

// ---------------------------------------------------------------------------
// Fallback: naive direct conv (used only if ws_size too small)
// ---------------------------------------------------------------------------
__global__ __launch_bounds__(256) void k_naive(const float* __restrict__ x,
                                               const float* __restrict__ wgt,
                                               const float* __restrict__ bias,
                                               float* __restrict__ out) {
    int idx = blockIdx.x * 256 + threadIdx.x;
    int ow = idx & 31, oh = (idx >> 5) & 31, o = (idx >> 10) & 63, b = idx >> 16;
    float acc = bias[(o * 32 + oh) * 32 + ow];
    const float* wp = wgt + ((size_t)(oh * 32 + ow) * 64 + o) * 576;
    for (int c = 0; c < 64; ++c) {
        for (int kh = 0; kh < 3; ++kh) {
            int hh = oh + kh - 1;
            if ((unsigned)hh >= 32u) continue;
            for (int kw = 0; kw < 3; ++kw) {
                int ww = ow + kw - 1;
                if ((unsigned)ww >= 32u) continue;
                acc += x[((size_t)(b * 64 + c) * 32 + hh) * 32 + ww] * wp[c * 9 + kh * 3 + kw];
            }
        }
    }
    out[idx] = acc;
}

extern "C" void kernel_launch(void* const* d_in, const int* in_sizes, int n_in,
                              void* d_out, int out_size, void* d_ws, size_t ws_size,
                              hipStream_t stream) {
    const float* x    = (const float*)d_in[0];
    const float* wgt  = (const float*)d_in[1];
    const float* bias = (const float*)d_in[2];
    float* out = (float*)d_out;

    const size_t xt_bytes  = (size_t)32 * 32 * 64 * 64 * 2;   // 8.39 MB
    const size_t ws2_bytes = (size_t)1024 * 4096 * 4;         // 16.78 MB

    if (ws_size >= xt_bytes + ws2_bytes) {
        unsigned short* xt = (unsigned short*)d_ws;
        float* ws2 = (float*)((char*)d_ws + xt_bytes);
        k_xt<<<dim3(32, 8), 256, 0, stream>>>(x, xt);
        k_main<<<1024, 256, 0, stream>>>(wgt, xt, bias, ws2);
        k_out<<<1024, 256, 0, stream>>>(ws2, out);
    } else {
        k_naive<<<(64 * 64 * 32 * 32) / 256, 256, 0, stream>>>(x, wgt, bias, out);
    }
}

// Round 2
// 46.122 us; speedup vs baseline: 1.0538x; 1.0538x over previous
//
#include <hip/hip_runtime.h>
#include <hip/hip_bf16.h>

typedef __attribute__((ext_vector_type(8))) short short8;
typedef __attribute__((ext_vector_type(4))) float f32x4;

// fp32 -> bf16 round-to-nearest-even (finite inputs)
__device__ __forceinline__ unsigned short f2bf(float f) {
    union { float f; unsigned int u; } v; v.f = f;
    unsigned int u = v.u;
    u = (u + 0x7FFFu + ((u >> 16) & 1u)) >> 16;
    return (unsigned short)u;
}

// ---------------------------------------------------------------------------
// Kernel 1: x[b][c][h][w] f32  ->  xt[h][w][c][b] bf16
// ---------------------------------------------------------------------------
__global__ __launch_bounds__(256) void k_xt(const float* __restrict__ x,
                                            unsigned short* __restrict__ xt) {
    const int h  = blockIdx.x;   // 0..31
    const int cg = blockIdx.y;   // 0..7
    const int t  = threadIdx.x;
    __shared__ unsigned short L[32 * 520];

    #pragma unroll
    for (int i = 0; i < 16; ++i) {
        int s   = t + i * 256;
        int row = s >> 3;
        int wq  = s & 7;
        int b = row >> 3, c = row & 7;
        const f32x4 v = *(const f32x4*)(x + (((size_t)(b * 64 + cg * 8 + c) * 32 + h) * 32 + wq * 4));
        int base = c * 64 + b;
        L[(wq * 4 + 0) * 520 + base] = f2bf(v[0]);
        L[(wq * 4 + 1) * 520 + base] = f2bf(v[1]);
        L[(wq * 4 + 2) * 520 + base] = f2bf(v[2]);
        L[(wq * 4 + 3) * 520 + base] = f2bf(v[3]);
    }
    __syncthreads();
    #pragma unroll
    for (int i = 0; i < 8; ++i) {
        int s  = t + i * 256;
        int w  = s >> 6;
        int ch = s & 63;
        short8 v = *(const short8*)&L[w * 520 + ch * 8];
        *(short8*)(xt + (((size_t)(h * 32 + w) * 64 + cg * 8) * 64 + ch * 8)) = v;
    }
}

// ---------------------------------------------------------------------------
// Kernel 2: per-location GEMM, software-pipelined.
// One block per l. Double-buffered LDS, raw barriers (loads stay in flight),
// bf16 intermediate output ws2b[l][b][o].
// ---------------------------------------------------------------------------
__global__ __launch_bounds__(256) void k_main(const float* __restrict__ wgt,
                                              const unsigned short* __restrict__ xt,
                                              const float* __restrict__ bias,
                                              unsigned short* __restrict__ ws2b) {
    const int bid = blockIdx.x;
    const int l   = (bid & 7) * 128 + (bid >> 3);   // XCD swizzle (1024 % 8 == 0, bijective)
    const int oh = l >> 5, ow = l & 31;
    const int t  = threadIdx.x;
    const int wave = t >> 6, lane = t & 63;
    const int wm = wave >> 1, wn = wave & 1;

    __shared__ unsigned short Ash[2][64 * 72];  // [b][k], +8 pad
    __shared__ unsigned short Bsh[2][64 * 72];  // [o][k], +8 pad

    f32x4 acc[2][2];
    #pragma unroll
    for (int i = 0; i < 2; ++i)
        #pragma unroll
        for (int j = 0; j < 2; ++j)
            acc[i][j] = (f32x4){0.f, 0.f, 0.f, 0.f};

    const float* wslab = wgt + (size_t)l * (64 * 576);
    const int b0 = wave * 16;
    const int o  = t >> 2, kp = t & 3;
    const float* bbase = wslab + o * 576 + kp * 16;

    auto loadA = [&](int kt, short8& va, short8& vb) {
        int kk = kt * 64 + lane;      // 0..575
        int c  = kk / 9;
        int r  = kk - c * 9;
        int kh = r / 3;
        int kw = r - kh * 3;
        int hh = oh + kh - 1;
        int ww = ow + kw - 1;
        va = (short8){0,0,0,0,0,0,0,0};
        vb = (short8){0,0,0,0,0,0,0,0};
        if ((unsigned)hh < 32u && (unsigned)ww < 32u) {
            const unsigned short* src = xt + (((size_t)(hh * 32 + ww) * 64 + c) * 64 + b0);
            va = *(const short8*)src;
            vb = *(const short8*)(src + 8);
        }
    };
    auto loadB = [&](int kt, f32x4& w0, f32x4& w1, f32x4& w2, f32x4& w3) {
        const f32x4* bp = (const f32x4*)(bbase + kt * 64);
        w0 = bp[0]; w1 = bp[1]; w2 = bp[2]; w3 = bp[3];
    };

    short8 cA0, cA1;
    short8 nA0 = (short8){0,0,0,0,0,0,0,0}, nA1 = (short8){0,0,0,0,0,0,0,0};
    f32x4 cB0, cB1, cB2, cB3;
    f32x4 nB0 = (f32x4){0,0,0,0}, nB1 = nB0, nB2 = nB0, nB3 = nB0;

    loadA(0, cA0, cA1);
    loadB(0, cB0, cB1, cB2, cB3);

    for (int kt = 0; kt < 9; ++kt) {
        const int p = kt & 1;
        // issue next tile's loads FIRST — they stay in flight across the raw barrier
        if (kt < 8) {
            loadA(kt + 1, nA0, nA1);
            loadB(kt + 1, nB0, nB1, nB2, nB3);
        }
        // stage A (b16 scatter: [b][k] transpose)
        #pragma unroll
        for (int j = 0; j < 8; ++j) Ash[p][(b0 + j) * 72 + lane] = (unsigned short)cA0[j];
        #pragma unroll
        for (int j = 0; j < 8; ++j) Ash[p][(b0 + 8 + j) * 72 + lane] = (unsigned short)cA1[j];
        // stage B (convert + write)
        {
            short8 p0, p1;
            p0[0] = (short)f2bf(cB0[0]); p0[1] = (short)f2bf(cB0[1]);
            p0[2] = (short)f2bf(cB0[2]); p0[3] = (short)f2bf(cB0[3]);
            p0[4] = (short)f2bf(cB1[0]); p0[5] = (short)f2bf(cB1[1]);
            p0[6] = (short)f2bf(cB1[2]); p0[7] = (short)f2bf(cB1[3]);
            p1[0] = (short)f2bf(cB2[0]); p1[1] = (short)f2bf(cB2[1]);
            p1[2] = (short)f2bf(cB2[2]); p1[3] = (short)f2bf(cB2[3]);
            p1[4] = (short)f2bf(cB3[0]); p1[5] = (short)f2bf(cB3[1]);
            p1[6] = (short)f2bf(cB3[2]); p1[7] = (short)f2bf(cB3[3]);
            unsigned short* bdst = &Bsh[p][o * 72 + kp * 16];
            *(short8*)bdst       = p0;
            *(short8*)(bdst + 8) = p1;
        }
        // own LDS writes visible, then barrier; do NOT drain vmcnt
        asm volatile("s_waitcnt lgkmcnt(0)" ::: "memory");
        __builtin_amdgcn_s_barrier();
        __builtin_amdgcn_sched_barrier(0);
        // MFMA phase
        #pragma unroll
        for (int ks = 0; ks < 2; ++ks) {
            int kof = ks * 32 + (lane >> 4) * 8;
            short8 a0 = *(const short8*)&Ash[p][(wm * 32 + (lane & 15)) * 72 + kof];
            short8 a1 = *(const short8*)&Ash[p][(wm * 32 + 16 + (lane & 15)) * 72 + kof];
            short8 q0 = *(const short8*)&Bsh[p][(wn * 32 + (lane & 15)) * 72 + kof];
            short8 q1 = *(const short8*)&Bsh[p][(wn * 32 + 16 + (lane & 15)) * 72 + kof];
            acc[0][0] = __builtin_amdgcn_mfma_f32_16x16x32_bf16(a0, q0, acc[0][0], 0, 0, 0);
            acc[0][1] = __builtin_amdgcn_mfma_f32_16x16x32_bf16(a0, q1, acc[0][1], 0, 0, 0);
            acc[1][0] = __builtin_amdgcn_mfma_f32_16x16x32_bf16(a1, q0, acc[1][0], 0, 0, 0);
            acc[1][1] = __builtin_amdgcn_mfma_f32_16x16x32_bf16(a1, q1, acc[1][1], 0, 0, 0);
        }
        cA0 = nA0; cA1 = nA1;
        cB0 = nB0; cB1 = nB1; cB2 = nB2; cB3 = nB3;
    }

    // epilogue: +bias, convert to bf16, write ws2b[l][b*64+o]
    const int col = lane & 15;
    const int rq  = (lane >> 4) * 4;
    #pragma unroll
    for (int j = 0; j < 2; ++j) {
        int n = wn * 32 + j * 16 + col;
        float bv = bias[n * 1024 + l];
        #pragma unroll
        for (int i = 0; i < 2; ++i) {
            int mbase = wm * 32 + i * 16 + rq;
            #pragma unroll
            for (int q = 0; q < 4; ++q) {
                ws2b[(size_t)l * 4096 + (size_t)(mbase + q) * 64 + n] = f2bf(acc[i][j][q] + bv);
            }
        }
    }
}

// ---------------------------------------------------------------------------
// Kernel 3: ws2b[1024 l][4096 m] bf16 -> out[4096 m][1024 l] f32
// ---------------------------------------------------------------------------
__global__ __launch_bounds__(256) void k_out(const unsigned short* __restrict__ ws2b,
                                             float* __restrict__ out) {
    const int bx = blockIdx.x;
    const int lt = bx & 15;    // l tile (16)
    const int mt = bx >> 4;    // m tile (64)
    const int t  = threadIdx.x;
    __shared__ float T[64 * 65];
    const int l0 = lt * 64, m0 = mt * 64;

    #pragma unroll
    for (int i = 0; i < 2; ++i) {
        int s  = t + i * 256;       // 0..511
        int lr = s >> 3;            // 0..63
        int mc = (s & 7) * 8;       // 0..56
        short8 v = *(const short8*)&ws2b[(size_t)(l0 + lr) * 4096 + m0 + mc];
        #pragma unroll
        for (int j = 0; j < 8; ++j) {
            union { unsigned int u; float f; } w;
            w.u = ((unsigned int)(unsigned short)v[j]) << 16;
            T[lr * 65 + mc + j] = w.f;
        }
    }
    __syncthreads();
    #pragma unroll
    for (int i = 0; i < 4; ++i) {
        int s  = t + i * 256;       // 0..1023
        int mr = s >> 4;            // 0..63
        int lc = (s & 15) * 4;
        f32x4 v;
        v[0] = T[(lc + 0) * 65 + mr];
        v[1] = T[(lc + 1) * 65 + mr];
        v[2] = T[(lc + 2) * 65 + mr];
        v[3] = T[(lc + 3) * 65 + mr];
        *(f32x4*)(out + (size_t)(m0 + mr) * 1024 + l0 + lc) = v;
    }
}

// ---------------------------------------------------------------------------
// Fallback: naive direct conv (used only if ws_size too small)
// ---------------------------------------------------------------------------
__global__ __launch_bounds__(256) void k_naive(const float* __restrict__ x,
                                               const float* __restrict__ wgt,
                                               const float* __restrict__ bias,
                                               float* __restrict__ out) {
    int idx = blockIdx.x * 256 + threadIdx.x;
    int ow = idx & 31, oh = (idx >> 5) & 31, o = (idx >> 10) & 63, b = idx >> 16;
    float acc = bias[(o * 32 + oh) * 32 + ow];
    const float* wp = wgt + ((size_t)(oh * 32 + ow) * 64 + o) * 576;
    for (int c = 0; c < 64; ++c) {
        for (int kh = 0; kh < 3; ++kh) {
            int hh = oh + kh - 1;
            if ((unsigned)hh >= 32u) continue;
            for (int kw = 0; kw < 3; ++kw) {
                int ww = ow + kw - 1;
                if ((unsigned)ww >= 32u) continue;
                acc += x[((size_t)(b * 64 + c) * 32 + hh) * 32 + ww] * wp[c * 9 + kh * 3 + kw];
            }
        }
    }
    out[idx] = acc;
}

extern "C" void kernel_launch(void* const* d_in, const int* in_sizes, int n_in,
                              void* d_out, int out_size, void* d_ws, size_t ws_size,
                              hipStream_t stream) {
    const float* x    = (const float*)d_in[0];
    const float* wgt  = (const float*)d_in[1];
    const float* bias = (const float*)d_in[2];
    float* out = (float*)d_out;

    const size_t xt_bytes  = (size_t)32 * 32 * 64 * 64 * 2;   // 8.39 MB
    const size_t ws2_bytes = (size_t)1024 * 4096 * 2;         // 8.39 MB (bf16)

    if (ws_size >= xt_bytes + ws2_bytes) {
        unsigned short* xt   = (unsigned short*)d_ws;
        unsigned short* ws2b = (unsigned short*)((char*)d_ws + xt_bytes);
        k_xt<<<dim3(32, 8), 256, 0, stream>>>(x, xt);
        k_main<<<1024, 256, 0, stream>>>(wgt, xt, bias, ws2b);
        k_out<<<1024, 256, 0, stream>>>(ws2b, out);
    } else {
        k_naive<<<(64 * 64 * 32 * 32) / 256, 256, 0, stream>>>(x, wgt, bias, out);
    }
}